// Round 3
// baseline (513.460 us; speedup 1.0000x reference)
//
#include <hip/hip_runtime.h>

typedef __bf16 bf16;
typedef __bf16 bf16x8 __attribute__((ext_vector_type(8)));
typedef float f32x4 __attribute__((ext_vector_type(4)));

#define B_ 2
#define S_ 2048
#define D_ 2048
#define H_ 16
#define DH_ 128
#define QKVN 6144

__device__ __forceinline__ void async_load16(const bf16* g, bf16* l) {
    __builtin_amdgcn_global_load_lds((const __attribute__((address_space(1))) void*)g,
                                     (__attribute__((address_space(3))) void*)l, 16, 0, 0);
}

__device__ __forceinline__ unsigned int bf16_bits(float x) {
    bf16 h = (bf16)x;
    return (unsigned int)__builtin_bit_cast(unsigned short, h);
}

// ---------------- x cast: f32 -> bf16, 8 elems/thread -----------------------------
__global__ __launch_bounds__(256) void cvt_kernel(const float* __restrict__ src,
                                                  bf16* __restrict__ dst) {
    size_t i = (size_t)blockIdx.x * 256 + threadIdx.x;
    const float4* s = (const float4*)src;
    float4 a = s[2 * i], b = s[2 * i + 1];
    bf16x8 o;
    o[0] = (bf16)a.x; o[1] = (bf16)a.y; o[2] = (bf16)a.z; o[3] = (bf16)a.w;
    o[4] = (bf16)b.x; o[5] = (bf16)b.y; o[6] = (bf16)b.z; o[7] = (bf16)b.w;
    *(bf16x8*)(dst + 8 * i) = o;
}

// ------- weight transpose + cast: W[K][N] f32 -> Wt[N][K] bf16, 4 matrices --------
__global__ __launch_bounds__(256) void wtrans_kernel(const float* __restrict__ Wq,
                                                     const float* __restrict__ Wk,
                                                     const float* __restrict__ Wv,
                                                     const float* __restrict__ Wo,
                                                     bf16* __restrict__ WqkvT,
                                                     bf16* __restrict__ WoT) {
    __shared__ unsigned int tile[64][65];  // bf16 bits in low half
    int z = blockIdx.z;
    const float* src = (z == 0) ? Wq : (z == 1) ? Wk : (z == 2) ? Wv : Wo;
    bf16* dst = (z < 3) ? (WqkvT + (size_t)z * D_ * D_) : WoT;
    int r0 = blockIdx.y * 64, c0 = blockIdx.x * 64;
    int t = threadIdx.x;
    int tr = t >> 4, tc4 = (t & 15) * 4;
#pragma unroll
    for (int it = 0; it < 4; ++it) {
        int r = it * 16 + tr;
        float4 v = *(const float4*)(src + (size_t)(r0 + r) * D_ + c0 + tc4);
        tile[r][tc4 + 0] = bf16_bits(v.x);
        tile[r][tc4 + 1] = bf16_bits(v.y);
        tile[r][tc4 + 2] = bf16_bits(v.z);
        tile[r][tc4 + 3] = bf16_bits(v.w);
    }
    __syncthreads();
#pragma unroll
    for (int it = 0; it < 4; ++it) {
        int a = it * 16 + tr;
        unsigned u0 = tile[tc4 + 0][a], u1 = tile[tc4 + 1][a];
        unsigned u2 = tile[tc4 + 2][a], u3 = tile[tc4 + 3][a];
        uint2 v;
        v.x = (u0 & 0xffffu) | (u1 << 16);
        v.y = (u2 & 0xffffu) | (u3 << 16);
        *(uint2*)(dst + (size_t)(c0 + a) * D_ + r0 + tc4) = v;
    }
}

// ---------------- V transpose: qkv[:,4096+h*128+dh] -> vt[bh][dh][s], bf16 --------
__global__ __launch_bounds__(256) void vtrans_kernel(const bf16* __restrict__ qkv,
                                                     bf16* __restrict__ vt) {
    __shared__ unsigned int tile[64][65];
    int bh = blockIdx.z;
    int b = bh >> 4, h = bh & 15;
    int s0 = blockIdx.x * 64, d0 = blockIdx.y * 64;
    int t = threadIdx.x, tr = t >> 4, tc4 = (t & 15) * 4;
#pragma unroll
    for (int it = 0; it < 4; ++it) {
        int r = it * 16 + tr;  // s offset
        uint2 v = *(const uint2*)(qkv + (size_t)(b * S_ + s0 + r) * QKVN + 2 * D_ + h * DH_ + d0 + tc4);
        tile[r][tc4 + 0] = v.x & 0xffffu;
        tile[r][tc4 + 1] = v.x >> 16;
        tile[r][tc4 + 2] = v.y & 0xffffu;
        tile[r][tc4 + 3] = v.y >> 16;
    }
    __syncthreads();
#pragma unroll
    for (int it = 0; it < 4; ++it) {
        int a = it * 16 + tr;  // dh offset
        unsigned u0 = tile[tc4 + 0][a], u1 = tile[tc4 + 1][a];
        unsigned u2 = tile[tc4 + 2][a], u3 = tile[tc4 + 3][a];
        uint2 v;
        v.x = (u0 & 0xffffu) | (u1 << 16);
        v.y = (u2 & 0xffffu) | (u3 << 16);
        *(uint2*)(vt + (size_t)bh * DH_ * S_ + (size_t)(d0 + a) * S_ + s0 + tc4) = v;
    }
}

// ---------------- m97-style GEMM: C[M][N] = A[M][K] @ Bt[N][K]^T ------------------
// bf16 A/Bt; writes bf16 C (Cb) or f32 C (Cf) depending on which pointer is set.
template <typename CT>
__global__ __launch_bounds__(256) void gemm_bt(const bf16* __restrict__ A,
                                               const bf16* __restrict__ Bt,
                                               CT* __restrict__ C,
                                               int M, int N, int K) {
    __shared__ __align__(16) bf16 As[128 * 32];
    __shared__ __align__(16) bf16 Bs[128 * 32];
    int t = threadIdx.x;
    int w = t >> 6, l = t & 63;
    int quad = l >> 4, lr = l & 15;
    int wr = w >> 1, wc = w & 1;
    size_t m0 = (size_t)blockIdx.y * 128, n0 = (size_t)blockIdx.x * 128;
    int srow = l >> 2, scol = (l & 3) * 8;

    f32x4 acc[4][4];
#pragma unroll
    for (int i = 0; i < 4; ++i)
#pragma unroll
        for (int j = 0; j < 4; ++j) acc[i][j] = (f32x4){0.f, 0.f, 0.f, 0.f};

    for (int k0 = 0; k0 < K; k0 += 32) {
        __syncthreads();
#pragma unroll
        for (int i = 0; i < 2; ++i) {
            int c = w * 2 + i;
            async_load16(A + (m0 + c * 16 + srow) * (size_t)K + k0 + scol, As + c * 512);
            async_load16(Bt + (n0 + c * 16 + srow) * (size_t)K + k0 + scol, Bs + c * 512);
        }
        asm volatile("s_waitcnt vmcnt(0)" ::: "memory");
        __syncthreads();
        bf16x8 af[4], bfr[4];
#pragma unroll
        for (int i = 0; i < 4; ++i) af[i] = *(const bf16x8*)(As + (wr * 64 + i * 16 + lr) * 32 + quad * 8);
#pragma unroll
        for (int j = 0; j < 4; ++j) bfr[j] = *(const bf16x8*)(Bs + (wc * 64 + j * 16 + lr) * 32 + quad * 8);
#pragma unroll
        for (int i = 0; i < 4; ++i)
#pragma unroll
            for (int j = 0; j < 4; ++j)
                acc[i][j] = __builtin_amdgcn_mfma_f32_16x16x32_bf16(af[i], bfr[j], acc[i][j], 0, 0, 0);
    }

    size_t bm = m0 + wr * 64 + quad * 4;
    size_t bn = n0 + wc * 64 + lr;
#pragma unroll
    for (int i = 0; i < 4; ++i)
#pragma unroll
        for (int j = 0; j < 4; ++j)
#pragma unroll
            for (int r = 0; r < 4; ++r)
                C[(bm + i * 16 + r) * (size_t)N + bn + j * 16] = (CT)acc[i][j][r];
}

// ---------------- flash attention, causal (W=2048 never truncates at s=2048) ------
// grid: (32 q-tiles, 32 bh). block: 256 = 4 waves; wave w owns q rows [w*16,w*16+16)
__global__ __launch_bounds__(256) void attn_kernel(const bf16* __restrict__ qkv,
                                                   const bf16* __restrict__ vt,
                                                   bf16* __restrict__ ctx) {
    __shared__ __align__(16) bf16 Qs[64][136];
    __shared__ __align__(16) bf16 Ks[64][136];
    __shared__ __align__(16) bf16 Vts[128][72];
    __shared__ __align__(16) bf16 Ps[4][16][72];

    int qt = blockIdx.x, bh = blockIdx.y;
    int b = bh >> 4, h = bh & 15;
    int q0 = qt * 64;
    int t = threadIdx.x, w = t >> 6, l = t & 63;
    int quad = l >> 4, lr = l & 15;
    int sr = t >> 4, sc = (t & 15) * 8;
    int vr = t >> 3, vc = (t & 7) * 8;

    // stage Q tile once
#pragma unroll
    for (int it = 0; it < 4; ++it) {
        int r = it * 16 + sr;
        *(bf16x8*)&Qs[r][sc] = *(const bf16x8*)(qkv + (size_t)(b * S_ + q0 + r) * QKVN + h * DH_ + sc);
    }
    __syncthreads();
    bf16x8 qf[4];
#pragma unroll
    for (int kk = 0; kk < 4; ++kk) qf[kk] = *(const bf16x8*)&Qs[w * 16 + lr][kk * 32 + quad * 8];

    float m_r[4], l_r[4];
    f32x4 o[8];
#pragma unroll
    for (int r = 0; r < 4; ++r) { m_r[r] = -1e30f; l_r[r] = 0.f; }
#pragma unroll
    for (int nt = 0; nt < 8; ++nt) o[nt] = (f32x4){0.f, 0.f, 0.f, 0.f};

    const float scale = 0.08838834764831845f;  // 1/sqrt(128)

    for (int kt = 0; kt <= qt; ++kt) {
        __syncthreads();  // protect Ks/Vts reuse
#pragma unroll
        for (int it = 0; it < 4; ++it) {
            int r = it * 16 + sr;
            *(bf16x8*)&Ks[r][sc] = *(const bf16x8*)(qkv + (size_t)(b * S_ + kt * 64 + r) * QKVN + D_ + h * DH_ + sc);
        }
#pragma unroll
        for (int it = 0; it < 4; ++it) {
            int r = it * 32 + vr;
            *(bf16x8*)&Vts[r][vc] = *(const bf16x8*)(vt + (size_t)bh * DH_ * S_ + (size_t)r * S_ + kt * 64 + vc);
        }
        __syncthreads();

        // S strip = Q K^T (16 q-rows x 64 keys per wave)
        f32x4 s[4];
#pragma unroll
        for (int jt = 0; jt < 4; ++jt) {
            s[jt] = (f32x4){0.f, 0.f, 0.f, 0.f};
#pragma unroll
            for (int kk = 0; kk < 4; ++kk) {
                bf16x8 kf = *(const bf16x8*)&Ks[jt * 16 + lr][kk * 32 + quad * 8];
                s[jt] = __builtin_amdgcn_mfma_f32_16x16x32_bf16(qf[kk], kf, s[jt], 0, 0, 0);
            }
        }

        // scale + causal mask (only the diagonal tile has masked entries)
        int qrow = q0 + w * 16 + quad * 4;
        bool diag = (kt == qt);
#pragma unroll
        for (int jt = 0; jt < 4; ++jt)
#pragma unroll
            for (int r = 0; r < 4; ++r) {
                float v = s[jt][r] * scale;
                if (diag && (kt * 64 + jt * 16 + lr > qrow + r)) v = -1e30f;
                s[jt][r] = v;
            }

        // online softmax (each C row lives in a 16-lane group: lanes quad*16+lr)
        float mx[4];
#pragma unroll
        for (int r = 0; r < 4; ++r)
            mx[r] = fmaxf(fmaxf(s[0][r], s[1][r]), fmaxf(s[2][r], s[3][r]));
#pragma unroll
        for (int d = 1; d < 16; d <<= 1)
#pragma unroll
            for (int r = 0; r < 4; ++r) mx[r] = fmaxf(mx[r], __shfl_xor(mx[r], d, 64));

        float alpha[4];
#pragma unroll
        for (int r = 0; r < 4; ++r) {
            float mn = fmaxf(m_r[r], mx[r]);
            alpha[r] = __expf(m_r[r] - mn);
            m_r[r] = mn;
        }
        float rs[4] = {0.f, 0.f, 0.f, 0.f};
#pragma unroll
        for (int jt = 0; jt < 4; ++jt)
#pragma unroll
            for (int r = 0; r < 4; ++r) {
                float p = __expf(s[jt][r] - m_r[r]);
                s[jt][r] = p;
                rs[r] += p;
            }
#pragma unroll
        for (int d = 1; d < 16; d <<= 1)
#pragma unroll
            for (int r = 0; r < 4; ++r) rs[r] += __shfl_xor(rs[r], d, 64);
#pragma unroll
        for (int r = 0; r < 4; ++r) l_r[r] = l_r[r] * alpha[r] + rs[r];
#pragma unroll
        for (int nt = 0; nt < 8; ++nt)
#pragma unroll
            for (int r = 0; r < 4; ++r) o[nt][r] *= alpha[r];

        // P: C-layout -> LDS -> A-layout; __syncthreads is the fence
#pragma unroll
        for (int jt = 0; jt < 4; ++jt)
#pragma unroll
            for (int r = 0; r < 4; ++r)
                Ps[w][quad * 4 + r][jt * 16 + lr] = (bf16)s[jt][r];
        __syncthreads();

        // O += P @ V
#pragma unroll
        for (int ks = 0; ks < 2; ++ks) {
            bf16x8 pf = *(const bf16x8*)&Ps[w][lr][ks * 32 + quad * 8];
#pragma unroll
            for (int nt = 0; nt < 8; ++nt) {
                bf16x8 vf = *(const bf16x8*)&Vts[nt * 16 + lr][ks * 32 + quad * 8];
                o[nt] = __builtin_amdgcn_mfma_f32_16x16x32_bf16(pf, vf, o[nt], 0, 0, 0);
            }
        }
    }

    // epilogue: ctx[b,q,h,dh] bf16
#pragma unroll
    for (int nt = 0; nt < 8; ++nt) {
#pragma unroll
        for (int r = 0; r < 4; ++r) {
            float v = o[nt][r] / l_r[r];
            int q = q0 + w * 16 + quad * 4 + r;
            ctx[(size_t)(b * S_ + q) * D_ + h * DH_ + nt * 16 + lr] = (bf16)v;
        }
    }
}

extern "C" void kernel_launch(void* const* d_in, const int* in_sizes, int n_in,
                              void* d_out, int out_size, void* d_ws, size_t ws_size,
                              hipStream_t stream) {
    // Reference dtypes are float32 (jnp.float32) — inputs/outputs are f32.
    const float* x  = (const float*)d_in[0];
    const float* Wq = (const float*)d_in[1];
    const float* Wk = (const float*)d_in[2];
    const float* Wv = (const float*)d_in[3];
    const float* Wo = (const float*)d_in[4];
    float* out = (float*)d_out;

    char* ws = (char*)d_ws;
    bf16* WqkvT = (bf16*)(ws);                       // 3*2048*2048*2 = 25165824
    bf16* WoT   = (bf16*)(ws + 25165824);            // 2048*2048*2   =  8388608
    bf16* qkv   = (bf16*)(ws + 33554432);            // 4096*6144*2   = 50331648
    bf16* vt    = (bf16*)(ws + 83886080);            // 32*128*2048*2 = 16777216
    bf16* ctx   = (bf16*)(ws + 100663296);           // 4096*2048*2   = 16777216
    bf16* xb    = (bf16*)(ws + 117440512);           // 4096*2048*2   = 16777216
    // total ws use: 134217728 bytes (128 MiB)

    cvt_kernel<<<4096, 256, 0, stream>>>(x, xb);     // 8388608 elems / 8 per thread
    wtrans_kernel<<<dim3(32, 32, 4), 256, 0, stream>>>(Wq, Wk, Wv, Wo, WqkvT, WoT);
    gemm_bt<bf16><<<dim3(48, 32), 256, 0, stream>>>(xb, WqkvT, qkv, B_ * S_, QKVN, D_);
    vtrans_kernel<<<dim3(32, 2, 32), 256, 0, stream>>>(qkv, vt);
    attn_kernel<<<dim3(32, 32), 256, 0, stream>>>(qkv, vt, ctx);
    gemm_bt<float><<<dim3(16, 32), 256, 0, stream>>>(ctx, WoT, out, B_ * S_, D_, D_);
}